// Round 4
// baseline (188.920 us; speedup 1.0000x reference)
//
#include <hip/hip_runtime.h>
#include <math.h>
#include <stdint.h>

// out[b,c,h,w] = tanh(weight[idx,c] * img[b,c,h,w] + bias[idx,c])
// idx = (int32)(q0*65536 + q1*256 + q2), q_c = (img_c + 1)*127.5  (exact fp32, no fma)
//
// R4 design: R3's fused bf16 table (12 B/row) -> pad to 16 B/row so each pixel
// gather is ONE aligned global_load_dwordx4 (was 3 dword loads, 19% of rows
// straddling a 64B line). Table = 134 MB, Infinity-Cache-resident after the
// build pass. Build pass vectorized: 4 rows/thread, dwordx4 nt loads.
// R2 lesson: random-line fetch is throughput-capped (~3 TB/s vs HBM) -> win by
// fewer random lines + fewer VMEM instructions, not more MLP.

#define HW_   (512 * 512)
#define CHW_  (3 * HW_)
#define PPT   8
#define GROUPS_PER_IMG (HW_ / PPT)
#define N_GROUPS (16 * GROUPS_PER_IMG)

#define LUT_BASE 8388607
#define LUT_ROWS 8388609             // idx in [8388607, 16777215] for img in [0,1)
#define COMBINED_BYTES ((size_t)LUT_ROWS * 16)

typedef float f4  __attribute__((ext_vector_type(4)));
typedef float f4a __attribute__((ext_vector_type(4), aligned(4)));  // 4B-aligned dwordx4

static __device__ __forceinline__ uint32_t f2bf(float f) {
    uint32_t u = __float_as_uint(f);
    return (u + 0x7FFFu + ((u >> 16) & 1u)) >> 16;   // RNE fp32->bf16
}
static __device__ __forceinline__ float bf_lo(uint32_t w) { return __uint_as_float(w << 16); }
static __device__ __forceinline__ float bf_hi(uint32_t w) { return __uint_as_float(w & 0xFFFF0000u); }

static __device__ __forceinline__ uint4 pack_row(float w0, float w1, float w2,
                                                 float b0, float b1, float b2) {
    uint4 r;
    r.x = f2bf(w0) | (f2bf(w1) << 16);
    r.y = f2bf(w2) | (f2bf(b0) << 16);
    r.z = f2bf(b1) | (f2bf(b2) << 16);
    r.w = 0u;
    return r;
}

// ---------------- Pass 1: build fused bf16 table, 4 rows/thread ----------------
#define BUILD_T ((LUT_ROWS + 3) / 4)   // 2,097,153 threads

__global__ __launch_bounds__(256) void
build_combined_kernel(const float* __restrict__ weight,
                      const float* __restrict__ bias,
                      uint4* __restrict__ comb) {
    size_t t = (size_t)blockIdx.x * 256 + threadIdx.x;
    if (t >= BUILD_T) return;
    size_t j4 = t * 4;

    if (j4 + 4 <= LUT_ROWS) {
        const float* wb = weight + (size_t)(LUT_BASE + j4) * 3;
        const float* bb = bias   + (size_t)(LUT_BASE + j4) * 3;
        // 12 consecutive floats from each table (3 x dwordx4, 4B-aligned ok)
        f4a w0 = __builtin_nontemporal_load((const f4a*)wb);
        f4a w1 = __builtin_nontemporal_load((const f4a*)wb + 1);
        f4a w2 = __builtin_nontemporal_load((const f4a*)wb + 2);
        f4a b0 = __builtin_nontemporal_load((const f4a*)bb);
        f4a b1 = __builtin_nontemporal_load((const f4a*)bb + 1);
        f4a b2 = __builtin_nontemporal_load((const f4a*)bb + 2);
        // rows: {w0.x w0.y w0.z} {w0.w w1.x w1.y} {w1.z w1.w w2.x} {w2.y w2.z w2.w}
        comb[j4 + 0] = pack_row(w0.x, w0.y, w0.z, b0.x, b0.y, b0.z);
        comb[j4 + 1] = pack_row(w0.w, w1.x, w1.y, b0.w, b1.x, b1.y);
        comb[j4 + 2] = pack_row(w1.z, w1.w, w2.x, b1.z, b1.w, b2.x);
        comb[j4 + 3] = pack_row(w2.y, w2.z, w2.w, b2.y, b2.z, b2.w);
    } else {
        for (size_t j = j4; j < LUT_ROWS; ++j) {
            size_t r = (size_t)(LUT_BASE + j) * 3;
            comb[j] = pack_row(weight[r], weight[r + 1], weight[r + 2],
                               bias[r],   bias[r + 1],   bias[r + 2]);
        }
    }
}

// ---------------- Pass 2: gather + affine + tanh ----------------
__global__ __launch_bounds__(256) void
gather_tanh_kernel(const float* __restrict__ img,
                   const uint4* __restrict__ comb,
                   const float* __restrict__ weight,   // fallback only
                   const float* __restrict__ bias,     // fallback only
                   float* __restrict__ out) {
    int t = blockIdx.x * blockDim.x + threadIdx.x;
    if (t >= N_GROUPS) return;

    int b = t >> 15;
    int p = (t & (GROUPS_PER_IMG - 1)) << 3;

    const float* base = img + (size_t)b * CHW_ + p;
    f4 r0 = __builtin_nontemporal_load((const f4*)(base));
    f4 r1 = __builtin_nontemporal_load((const f4*)(base + 4));
    f4 g0 = __builtin_nontemporal_load((const f4*)(base + HW_));
    f4 g1 = __builtin_nontemporal_load((const f4*)(base + HW_ + 4));
    f4 c0 = __builtin_nontemporal_load((const f4*)(base + 2 * HW_));
    f4 c1 = __builtin_nontemporal_load((const f4*)(base + 2 * HW_ + 4));

    float xr[PPT] = {r0.x, r0.y, r0.z, r0.w, r1.x, r1.y, r1.z, r1.w};
    float xg[PPT] = {g0.x, g0.y, g0.z, g0.w, g1.x, g1.y, g1.z, g1.w};
    float xb[PPT] = {c0.x, c0.y, c0.z, c0.w, c1.x, c1.y, c1.z, c1.w};

    // Stage 1: exact-fp32 index math (bit-matches numpy; never fma-contracted)
    int idx[PPT];
#pragma unroll
    for (int i = 0; i < PPT; ++i) {
        float q0 = __fmul_rn(__fadd_rn(xr[i], 1.0f), 127.5f);
        float q1 = __fmul_rn(__fadd_rn(xg[i], 1.0f), 127.5f);
        float q2 = __fmul_rn(__fadd_rn(xb[i], 1.0f), 127.5f);
        float s  = __fadd_rn(__fadd_rn(__fmul_rn(q0, 65536.0f),
                                       __fmul_rn(q1, 256.0f)),
                             q2);
        idx[i] = (int)s;
    }

    // Stage 2: ONE aligned dwordx4 gather per pixel, all issued before use
    uint4 cw[PPT];
    bool inr[PPT];
#pragma unroll
    for (int i = 0; i < PPT; ++i) {
        int cj = idx[i] - LUT_BASE;
        inr[i] = ((unsigned)cj < (unsigned)LUT_ROWS);
        cw[i] = comb[inr[i] ? cj : 0];
    }

    // Stage 3: unpack + fused affine + tanh
    float orr[PPT], org[PPT], orb[PPT];
#pragma unroll
    for (int i = 0; i < PPT; ++i) {
        float w0 = bf_lo(cw[i].x), w1 = bf_hi(cw[i].x);
        float w2 = bf_lo(cw[i].y), b0 = bf_hi(cw[i].y);
        float b1 = bf_lo(cw[i].z), b2 = bf_hi(cw[i].z);
        if (!inr[i]) {   // unreachable for harness inputs; kept for correctness
            const float* wr = weight + (size_t)idx[i] * 3;
            const float* br = bias   + (size_t)idx[i] * 3;
            w0 = wr[0]; w1 = wr[1]; w2 = wr[2];
            b0 = br[0]; b1 = br[1]; b2 = br[2];
        }
        orr[i] = tanhf(fmaf(w0, xr[i], b0));
        org[i] = tanhf(fmaf(w1, xg[i], b1));
        orb[i] = tanhf(fmaf(w2, xb[i], b2));
    }

    float* obase = out + (size_t)b * CHW_ + p;
    f4 v;
    v = (f4){orr[0], orr[1], orr[2], orr[3]}; __builtin_nontemporal_store(v, (f4*)(obase));
    v = (f4){orr[4], orr[5], orr[6], orr[7]}; __builtin_nontemporal_store(v, (f4*)(obase + 4));
    v = (f4){org[0], org[1], org[2], org[3]}; __builtin_nontemporal_store(v, (f4*)(obase + HW_));
    v = (f4){org[4], org[5], org[6], org[7]}; __builtin_nontemporal_store(v, (f4*)(obase + HW_ + 4));
    v = (f4){orb[0], orb[1], orb[2], orb[3]}; __builtin_nontemporal_store(v, (f4*)(obase + 2 * HW_));
    v = (f4){orb[4], orb[5], orb[6], orb[7]}; __builtin_nontemporal_store(v, (f4*)(obase + 2 * HW_ + 4));
}

// ---------------- Fallback: direct 2-table gather (R2 kernel) ----------------
__global__ __launch_bounds__(256) void
lut_affine_tanh_direct(const float* __restrict__ img,
                       const float* __restrict__ weight,
                       const float* __restrict__ bias,
                       float* __restrict__ out) {
    int t = blockIdx.x * blockDim.x + threadIdx.x;
    if (t >= N_GROUPS) return;
    int b = t >> 15;
    int p = (t & (GROUPS_PER_IMG - 1)) << 3;
    const float* base = img + (size_t)b * CHW_ + p;
    float4 r0 = *(const float4*)(base);
    float4 r1 = *(const float4*)(base + 4);
    float4 g0 = *(const float4*)(base + HW_);
    float4 g1 = *(const float4*)(base + HW_ + 4);
    float4 c0 = *(const float4*)(base + 2 * HW_);
    float4 c1 = *(const float4*)(base + 2 * HW_ + 4);
    float xr[PPT] = {r0.x, r0.y, r0.z, r0.w, r1.x, r1.y, r1.z, r1.w};
    float xg[PPT] = {g0.x, g0.y, g0.z, g0.w, g1.x, g1.y, g1.z, g1.w};
    float xb[PPT] = {c0.x, c0.y, c0.z, c0.w, c1.x, c1.y, c1.z, c1.w};
    int idx[PPT];
#pragma unroll
    for (int i = 0; i < PPT; ++i) {
        float q0 = __fmul_rn(__fadd_rn(xr[i], 1.0f), 127.5f);
        float q1 = __fmul_rn(__fadd_rn(xg[i], 1.0f), 127.5f);
        float q2 = __fmul_rn(__fadd_rn(xb[i], 1.0f), 127.5f);
        float s  = __fadd_rn(__fadd_rn(__fmul_rn(q0, 65536.0f),
                                       __fmul_rn(q1, 256.0f)), q2);
        idx[i] = (int)s;
    }
    float wv[PPT][3], bv[PPT][3];
#pragma unroll
    for (int i = 0; i < PPT; ++i) {
        const float* wr = weight + (size_t)idx[i] * 3;
        wv[i][0] = wr[0]; wv[i][1] = wr[1]; wv[i][2] = wr[2];
    }
#pragma unroll
    for (int i = 0; i < PPT; ++i) {
        const float* br = bias + (size_t)idx[i] * 3;
        bv[i][0] = br[0]; bv[i][1] = br[1]; bv[i][2] = br[2];
    }
    float orr[PPT], org[PPT], orb[PPT];
#pragma unroll
    for (int i = 0; i < PPT; ++i) {
        orr[i] = tanhf(fmaf(wv[i][0], xr[i], bv[i][0]));
        org[i] = tanhf(fmaf(wv[i][1], xg[i], bv[i][1]));
        orb[i] = tanhf(fmaf(wv[i][2], xb[i], bv[i][2]));
    }
    float* obase = out + (size_t)b * CHW_ + p;
    *(float4*)(obase)               = make_float4(orr[0], orr[1], orr[2], orr[3]);
    *(float4*)(obase + 4)           = make_float4(orr[4], orr[5], orr[6], orr[7]);
    *(float4*)(obase + HW_)         = make_float4(org[0], org[1], org[2], org[3]);
    *(float4*)(obase + HW_ + 4)     = make_float4(org[4], org[5], org[6], org[7]);
    *(float4*)(obase + 2 * HW_)     = make_float4(orb[0], orb[1], orb[2], orb[3]);
    *(float4*)(obase + 2 * HW_ + 4) = make_float4(orb[4], orb[5], orb[6], orb[7]);
}

extern "C" void kernel_launch(void* const* d_in, const int* in_sizes, int n_in,
                              void* d_out, int out_size, void* d_ws, size_t ws_size,
                              hipStream_t stream) {
    const float* img    = (const float*)d_in[0];
    const float* weight = (const float*)d_in[1];
    const float* bias   = (const float*)d_in[2];
    float* out = (float*)d_out;

    if (ws_size >= COMBINED_BYTES) {
        uint4* comb = (uint4*)d_ws;
        int bblocks = (int)((BUILD_T + 255) / 256);
        build_combined_kernel<<<bblocks, 256, 0, stream>>>(weight, bias, comb);
        gather_tanh_kernel<<<N_GROUPS / 256, 256, 0, stream>>>(img, comb, weight, bias, out);
    } else {
        lut_affine_tanh_direct<<<N_GROUPS / 256, 256, 0, stream>>>(img, weight, bias, out);
    }
}